// Round 3
// baseline (3363.326 us; speedup 1.0000x reference)
//
#include <hip/hip_runtime.h>
#include <stdint.h>

// ---------- bf16 helpers (bit-level, RNE) ----------
__device__ __forceinline__ float bf2f(unsigned short u){
  union { unsigned int i; float f; } x; x.i = ((unsigned int)u) << 16; return x.f;
}
__device__ __forceinline__ unsigned short f2bf(float f){
  union { float f; unsigned int i; } x; x.f = f;
  unsigned int r = x.i + 0x7fff + ((x.i >> 16) & 1);
  return (unsigned short)(r >> 16);
}
__device__ __forceinline__ void unpack8(uint4 v, float* o){
  o[0]=bf2f((unsigned short)(v.x)); o[1]=bf2f((unsigned short)(v.x>>16));
  o[2]=bf2f((unsigned short)(v.y)); o[3]=bf2f((unsigned short)(v.y>>16));
  o[4]=bf2f((unsigned short)(v.z)); o[5]=bf2f((unsigned short)(v.z>>16));
  o[6]=bf2f((unsigned short)(v.w)); o[7]=bf2f((unsigned short)(v.w>>16));
}
__device__ __forceinline__ uint4 pack8(const float* f){
  uint4 v;
  v.x = (unsigned)f2bf(f[0]) | ((unsigned)f2bf(f[1])<<16);
  v.y = (unsigned)f2bf(f[2]) | ((unsigned)f2bf(f[3])<<16);
  v.z = (unsigned)f2bf(f[4]) | ((unsigned)f2bf(f[5])<<16);
  v.w = (unsigned)f2bf(f[6]) | ((unsigned)f2bf(f[7])<<16);
  return v;
}
// bf16 row (16 ch) -> float[16]
__device__ __forceinline__ void loadrow16_bf(const unsigned short* p, float* in){
  uint4 a = *(const uint4*)p; uint4 b = *(const uint4*)(p+8);
  unpack8(a, in); unpack8(b, in+8);
}
// f32 row (16 ch) -> float[16]
__device__ __forceinline__ void loadrow16_f32(const float* p, float* in){
  float4 a = *(const float4*)p;      float4 b = *(const float4*)(p+4);
  float4 c = *(const float4*)(p+8);  float4 d = *(const float4*)(p+12);
  in[0]=a.x; in[1]=a.y; in[2]=a.z; in[3]=a.w;
  in[4]=b.x; in[5]=b.y; in[6]=b.z; in[7]=b.w;
  in[8]=c.x; in[9]=c.y; in[10]=c.z; in[11]=c.w;
  in[12]=d.x; in[13]=d.y; in[14]=d.z; in[15]=d.w;
}

// ---------- CSR build ----------
__global__ void k_count(const int* __restrict__ dst, int* __restrict__ cnt, int n){
  int i = blockIdx.x*blockDim.x + threadIdx.x;
  if (i < n) atomicAdd(&cnt[dst[i]], 1);
}

__global__ void k_blocksum(const int* __restrict__ cnt, int* __restrict__ bsum, int n){
  __shared__ int s[256];
  int i = blockIdx.x*256 + threadIdx.x;
  s[threadIdx.x] = (i < n) ? cnt[i] : 0;
  __syncthreads();
  for (int off=128; off>0; off>>=1){
    if (threadIdx.x < off) s[threadIdx.x] += s[threadIdx.x+off];
    __syncthreads();
  }
  if (threadIdx.x==0) bsum[blockIdx.x] = s[0];
}

__global__ void k_scan_bsum(int* bsum, int nb){
  __shared__ int s[256];
  __shared__ int carry;
  if (threadIdx.x==0) carry = 0;
  __syncthreads();
  for (int base=0; base<nb; base+=256){
    int i = base + threadIdx.x;
    int v = (i<nb) ? bsum[i] : 0;
    s[threadIdx.x] = v; __syncthreads();
    for (int off=1; off<256; off<<=1){
      int t = (threadIdx.x>=off) ? s[threadIdx.x-off] : 0;
      __syncthreads();
      s[threadIdx.x] += t;
      __syncthreads();
    }
    int excl = s[threadIdx.x] - v + carry;
    int tot  = s[255];
    if (i<nb) bsum[i] = excl;
    __syncthreads();
    if (threadIdx.x==0) carry += tot;
    __syncthreads();
  }
}

// cnt and cursor may alias (each thread reads its own cnt[i] before writing cursor[i])
__global__ void k_scan_add(const int* cnt, const int* __restrict__ bsum,
                           int* __restrict__ rowptr, int* cursor, int n){
  __shared__ int s[256];
  int i = blockIdx.x*256 + threadIdx.x;
  int v = (i<n) ? cnt[i] : 0;
  s[threadIdx.x] = v; __syncthreads();
  for (int off=1; off<256; off<<=1){
    int t = (threadIdx.x>=off) ? s[threadIdx.x-off] : 0;
    __syncthreads();
    s[threadIdx.x] += t;
    __syncthreads();
  }
  int excl = s[threadIdx.x] - v + bsum[blockIdx.x];
  if (i<n){
    rowptr[i] = excl;
    cursor[i] = excl;
    if (i == n-1) rowptr[n] = excl + v;
  }
}

__global__ void k_fill2(const int* __restrict__ src, const int* __restrict__ dst,
                        int* cursor, int* __restrict__ colA, int* __restrict__ colB, int n){
  int i = blockIdx.x*blockDim.x + threadIdx.x;
  if (i < n){
    int p = atomicAdd(&cursor[dst[i]], 1);
    colA[p] = src[i];
    if (colB) colB[p] = i;
  }
}

// ---------- gather spmm: out[v] = sum over CSR row of src[remap?remap[col]:col] ----------
// 2 threads per row, 8 channels each. Source either f32 rows or bf16 rows; out bf16.
template<bool F32SRC>
__global__ void __launch_bounds__(256) k_spmm(
    const int* __restrict__ rowptr, const int* __restrict__ col,
    const int* __restrict__ remap,
    const void* __restrict__ srcv, unsigned short* __restrict__ out, int nrows){
  int t = blockIdx.x*256 + threadIdx.x;
  int row = t >> 1, half = t & 1;
  if (row >= nrows) return;
  int beg = rowptr[row], end = rowptr[row+1];
  float acc[8] = {0,0,0,0,0,0,0,0};
  if (F32SRC){
    const float* sp = (const float*)srcv + (half<<3);
    for (int i=beg; i<end; ++i){
      int c = col[i];
      if (remap) c = remap[c];
      const float* p = sp + ((size_t)c<<4);
      float4 a = *(const float4*)p; float4 b = *(const float4*)(p+4);
      acc[0]+=a.x; acc[1]+=a.y; acc[2]+=a.z; acc[3]+=a.w;
      acc[4]+=b.x; acc[5]+=b.y; acc[6]+=b.z; acc[7]+=b.w;
    }
  } else {
    const unsigned short* sp = (const unsigned short*)srcv + (half<<3);
    for (int i=beg; i<end; ++i){
      int c = col[i];
      if (remap) c = remap[c];
      uint4 v = *(const uint4*)(sp + ((size_t)c<<4));
      float f[8]; unpack8(v, f);
      #pragma unroll
      for (int j=0;j<8;j++) acc[j] += f[j];
    }
  }
  *(uint4*)(out + ((size_t)row<<4) + (half<<3)) = pack8(acc);
}

// ---------- fused 6-way projection + bias + relu-merge + BN stats ----------
__device__ __forceinline__ void accum16(float* acc, const float* in, const float* w){
  #pragma unroll
  for (int o=0;o<32;o++){
    float a = acc[o];
    #pragma unroll
    for (int i=0;i<16;i++) a = fmaf(in[i], w[o*16+i], a);
    acc[o] = a;
  }
}

__global__ void __launch_bounds__(256) k_final(
    const float* __restrict__ base, const float* __restrict__ deg,
    const unsigned short* __restrict__ agg2, const unsigned short* __restrict__ z1,
    const unsigned short* __restrict__ z2, const unsigned short* __restrict__ z4,
    const float* __restrict__ W, const float* __restrict__ Bb,
    float* __restrict__ hout, float* __restrict__ stats, int nrows){
  __shared__ float sW[3072];
  __shared__ float sB[32];
  __shared__ float redS[4][16];
  __shared__ float redQ[4][16];
  for (int i=threadIdx.x; i<3072; i+=256) sW[i] = W[i];
  if (threadIdx.x < 32){
    float b = 0.f;
    #pragma unroll
    for (int k=0;k<6;k++) b += Bb[k*32 + threadIdx.x];
    sB[threadIdx.x] = b;
  }
  __syncthreads();
  float ssum[16], ssq[16];
  #pragma unroll
  for (int c=0;c<16;c++){ ssum[c]=0.f; ssq[c]=0.f; }

  for (long r = (long)blockIdx.x*256 + threadIdx.x; r < nrows; r += (long)gridDim.x*256){
    float acc[32];
    #pragma unroll
    for (int o=0;o<32;o++) acc[o] = sB[o];
    float in[16];
    loadrow16_f32(base + r*16, in);
    accum16(acc, in, sW);              // theta/gamma[0] : z
    float dg = deg[r];
    #pragma unroll
    for (int i=0;i<16;i++) in[i] *= dg;
    accum16(acc, in, sW + 512);        // [1] : deg * z
    loadrow16_bf(agg2 + r*16, in); accum16(acc, in, sW + 1024);  // [2] : yx / xy_agg
    loadrow16_bf(z1   + r*16, in); accum16(acc, in, sW + 1536);  // [3] : A z
    loadrow16_bf(z2   + r*16, in); accum16(acc, in, sW + 2048);  // [4] : A^2 z
    loadrow16_bf(z4   + r*16, in); accum16(acc, in, sW + 2560);  // [5] : A^4 z
    float h[16];
    #pragma unroll
    for (int c=0;c<16;c++) h[c] = acc[c] + fmaxf(acc[c+16], 0.f);
    float* op = hout + r*16;
    *(float4*)(op)      = make_float4(h[0],h[1],h[2],h[3]);
    *(float4*)(op + 4)  = make_float4(h[4],h[5],h[6],h[7]);
    *(float4*)(op + 8)  = make_float4(h[8],h[9],h[10],h[11]);
    *(float4*)(op + 12) = make_float4(h[12],h[13],h[14],h[15]);
    #pragma unroll
    for (int c=0;c<16;c++){ ssum[c] += h[c]; ssq[c] += h[c]*h[c]; }
  }

  int lane = threadIdx.x & 63, wid = threadIdx.x >> 6;
  #pragma unroll
  for (int c=0;c<16;c++){
    float s = ssum[c], q = ssq[c];
    for (int off=32; off; off>>=1){ s += __shfl_xor(s, off, 64); q += __shfl_xor(q, off, 64); }
    if (lane==0){ redS[wid][c] = s; redQ[wid][c] = q; }
  }
  __syncthreads();
  if (threadIdx.x < 16){
    float s=0.f, q=0.f;
    #pragma unroll
    for (int w4=0; w4<4; w4++){ s += redS[w4][threadIdx.x]; q += redQ[w4][threadIdx.x]; }
    atomicAdd(&stats[threadIdx.x], s);
    atomicAdd(&stats[16 + threadIdx.x], q);
  }
}

__global__ void k_stats(const float* __restrict__ st,
                        const float* __restrict__ wx, const float* __restrict__ bx,
                        const float* __restrict__ wy, const float* __restrict__ by,
                        float* __restrict__ prm, int nx, int ny){
  int c = threadIdx.x;
  if (c < 16){
    float m  = st[c]/(float)nx;
    float v  = st[16+c]/(float)nx - m*m;
    float sc = wx[c] * rsqrtf(v + 1e-5f);
    prm[c] = sc; prm[16+c] = bx[c] - m*sc;
    float m2  = st[32+c]/(float)ny;
    float v2  = st[48+c]/(float)ny - m2*m2;
    float sc2 = wy[c] * rsqrtf(v2 + 1e-5f);
    prm[32+c] = sc2; prm[48+c] = by[c] - m2*sc2;
  }
}

__global__ void k_norm(float* __restrict__ out, const float* __restrict__ prm,
                       long nx, long ntot){
  long g = ((long)blockIdx.x*256 + threadIdx.x) * 8;
  if (g >= ntot) return;
  const float* p = (g < nx) ? prm : prm + 32;
  int cbase = (int)(g & 15);
  float4 a = *(float4*)(out + g);
  float4 b = *(float4*)(out + g + 4);
  float f[8] = {a.x,a.y,a.z,a.w,b.x,b.y,b.z,b.w};
  #pragma unroll
  for (int j=0;j<8;j++){ int c = cbase + j; f[j] = f[j]*p[c] + p[16+c]; }
  *(float4*)(out + g)     = make_float4(f[0],f[1],f[2],f[3]);
  *(float4*)(out + g + 4) = make_float4(f[4],f[5],f[6],f[7]);
}

// ---------- host ----------
extern "C" void kernel_launch(void* const* d_in, const int* in_sizes, int n_in,
                              void* d_out, int out_size, void* d_ws, size_t ws_size,
                              hipStream_t stream){
  const float* x      = (const float*)d_in[0];
  const float* y      = (const float*)d_in[1];
  const float* deg_g  = (const float*)d_in[2];
  const float* deg_lg = (const float*)d_in[3];
  const float* thW    = (const float*)d_in[4];
  const float* thB    = (const float*)d_in[5];
  const float* gaW    = (const float*)d_in[6];
  const float* gaB    = (const float*)d_in[7];
  const float* bnxw   = (const float*)d_in[8];
  const float* bnxb   = (const float*)d_in[9];
  const float* bnyw   = (const float*)d_in[10];
  const float* bnyb   = (const float*)d_in[11];
  const int* src_g   = (const int*)d_in[12];
  const int* dst_g   = (const int*)d_in[13];
  const int* src_lg  = (const int*)d_in[14];
  const int* dst_lg  = (const int*)d_in[15];
  const int* eid2nid = (const int*)d_in[16];

  const int N  = in_sizes[2];   // deg_g is (N,1)
  const int E  = in_sizes[3];   // deg_lg is (E,1)
  const int EL = in_sizes[14];  // src_lg

  // workspace carve-out (256B aligned). Peak ~273 MB.
  char* w = (char*)d_ws;
  auto alloc = [&](size_t bytes)->void*{
    void* p = (void*)w; w += (bytes + 255) & ~(size_t)255; return p;
  };
  int* g_cnt      = (int*)alloc((size_t)N*4);        // counts, then cursor
  int* g_rowptr   = (int*)alloc((size_t)(N+1)*4);
  int* g_col_src  = (int*)alloc((size_t)E*4);
  int* g_col_eid  = (int*)alloc((size_t)E*4);
  int* lg_cnt     = (int*)alloc((size_t)E*4);
  int* lg_rowptr  = (int*)alloc((size_t)(E+1)*4);
  int* lg_col     = (int*)alloc((size_t)EL*4);
  int* bsum       = (int*)alloc(8192*4);
  float* stats    = (float*)alloc(64*4);             // x:[0..31], y:[32..63]
  float* prm      = (float*)alloc(64*4);             // scale/shift x, scale/shift y
  unsigned short* nz1 = (unsigned short*)alloc((size_t)N*16*2);
  unsigned short* nz2 = (unsigned short*)alloc((size_t)N*16*2);
  unsigned short* nz3 = (unsigned short*)alloc((size_t)N*16*2);
  unsigned short* nz4 = (unsigned short*)alloc((size_t)N*16*2);
  unsigned short* nyx = (unsigned short*)alloc((size_t)N*16*2);
  unsigned short* eb1 = (unsigned short*)alloc((size_t)E*16*2);
  unsigned short* eb2 = (unsigned short*)alloc((size_t)E*16*2);
  unsigned short* eb3 = (unsigned short*)alloc((size_t)E*16*2);  // B^3 y, then reused for xy_agg
  unsigned short* eb4 = (unsigned short*)alloc((size_t)E*16*2);

  hipMemsetAsync(g_cnt, 0, (size_t)N*4, stream);
  hipMemsetAsync(lg_cnt, 0, (size_t)E*4, stream);
  hipMemsetAsync(stats, 0, 64*4, stream);

  // ---- CSR for graph g (by dst_g, N rows) ----
  k_count<<<(E+255)/256, 256, 0, stream>>>(dst_g, g_cnt, E);
  int nbg = (N+255)/256;
  k_blocksum<<<nbg, 256, 0, stream>>>(g_cnt, bsum, N);
  k_scan_bsum<<<1, 256, 0, stream>>>(bsum, nbg);
  k_scan_add<<<nbg, 256, 0, stream>>>(g_cnt, bsum, g_rowptr, g_cnt, N);
  k_fill2<<<(E+255)/256, 256, 0, stream>>>(src_g, dst_g, g_cnt, g_col_src, g_col_eid, E);

  // ---- CSR for line graph (by dst_lg, E rows) ----
  k_count<<<(EL+255)/256, 256, 0, stream>>>(dst_lg, lg_cnt, EL);
  int nbl = (E+255)/256;
  k_blocksum<<<nbl, 256, 0, stream>>>(lg_cnt, bsum, E);
  k_scan_bsum<<<1, 256, 0, stream>>>(bsum, nbl);
  k_scan_add<<<nbl, 256, 0, stream>>>(lg_cnt, bsum, lg_rowptr, lg_cnt, E);
  k_fill2<<<(EL+255)/256, 256, 0, stream>>>(src_lg, dst_lg, lg_cnt, lg_col, (int*)nullptr, EL);

  // ---- node branch spmms ----
  int gs = (2*N+255)/256;
  k_spmm<true ><<<gs, 256, 0, stream>>>(g_rowptr, g_col_src, nullptr, x,   nz1, N); // A x
  k_spmm<false><<<gs, 256, 0, stream>>>(g_rowptr, g_col_src, nullptr, nz1, nz2, N); // A^2 x
  k_spmm<false><<<gs, 256, 0, stream>>>(g_rowptr, g_col_src, nullptr, nz2, nz3, N); // A^3 x
  k_spmm<false><<<gs, 256, 0, stream>>>(g_rowptr, g_col_src, nullptr, nz3, nz4, N); // A^4 x
  k_spmm<true ><<<gs, 256, 0, stream>>>(g_rowptr, g_col_eid, nullptr, y,   nyx, N); // sum_e y by dst

  // ---- edge branch spmms ----
  int es = (2*E+255)/256;
  k_spmm<true ><<<es, 256, 0, stream>>>(lg_rowptr, lg_col, nullptr, y,   eb1, E);   // B y
  k_spmm<false><<<es, 256, 0, stream>>>(lg_rowptr, lg_col, nullptr, eb1, eb2, E);   // B^2 y
  k_spmm<false><<<es, 256, 0, stream>>>(lg_rowptr, lg_col, nullptr, eb2, eb3, E);   // B^3 y
  k_spmm<false><<<es, 256, 0, stream>>>(lg_rowptr, lg_col, nullptr, eb3, eb4, E);   // B^4 y
  k_spmm<true ><<<es, 256, 0, stream>>>(lg_rowptr, lg_col, eid2nid, x,  eb3, E);    // B (x[eid2nid]) into eb3

  // ---- fused projections + h + BN stats ----
  float* outp = (float*)d_out;
  k_final<<<(N+1023)/1024, 256, 0, stream>>>(x, deg_g, nyx, nz1, nz2, nz4,
                                             thW, thB, outp, stats, N);
  k_final<<<(E+1023)/1024, 256, 0, stream>>>(y, deg_lg, eb3, eb1, eb2, eb4,
                                             gaW, gaB, outp + (size_t)N*16, stats + 32, E);

  // ---- BN finalize + normalize in place ----
  k_stats<<<1, 64, 0, stream>>>(stats, bnxw, bnxb, bnyw, bnyb, prm, N, E);
  long ntot = (long)(N + E) * 16;
  k_norm<<<(int)((ntot/8 + 255)/256), 256, 0, stream>>>(outp, prm, (long)N*16, ntot);
}

// Round 4
// 2222.008 us; speedup vs baseline: 1.5136x; 1.5136x over previous
//
#include <hip/hip_runtime.h>
#include <stdint.h>

// ---------- bf16 helpers (bit-level, RNE) ----------
__device__ __forceinline__ float bf2f(unsigned short u){
  union { unsigned int i; float f; } x; x.i = ((unsigned int)u) << 16; return x.f;
}
__device__ __forceinline__ unsigned short f2bf(float f){
  union { float f; unsigned int i; } x; x.f = f;
  unsigned int r = x.i + 0x7fff + ((x.i >> 16) & 1);
  return (unsigned short)(r >> 16);
}
__device__ __forceinline__ void unpack8(uint4 v, float* o){
  o[0]=bf2f((unsigned short)(v.x)); o[1]=bf2f((unsigned short)(v.x>>16));
  o[2]=bf2f((unsigned short)(v.y)); o[3]=bf2f((unsigned short)(v.y>>16));
  o[4]=bf2f((unsigned short)(v.z)); o[5]=bf2f((unsigned short)(v.z>>16));
  o[6]=bf2f((unsigned short)(v.w)); o[7]=bf2f((unsigned short)(v.w>>16));
}
__device__ __forceinline__ uint4 pack8(const float* f){
  uint4 v;
  v.x = (unsigned)f2bf(f[0]) | ((unsigned)f2bf(f[1])<<16);
  v.y = (unsigned)f2bf(f[2]) | ((unsigned)f2bf(f[3])<<16);
  v.z = (unsigned)f2bf(f[4]) | ((unsigned)f2bf(f[5])<<16);
  v.w = (unsigned)f2bf(f[6]) | ((unsigned)f2bf(f[7])<<16);
  return v;
}
__device__ __forceinline__ void loadrow16_bf(const unsigned short* p, float* in){
  uint4 a = *(const uint4*)p; uint4 b = *(const uint4*)(p+8);
  unpack8(a, in); unpack8(b, in+8);
}
__device__ __forceinline__ void loadrow16_f32(const float* p, float* in){
  float4 a = *(const float4*)p;      float4 b = *(const float4*)(p+4);
  float4 c = *(const float4*)(p+8);  float4 d = *(const float4*)(p+12);
  in[0]=a.x; in[1]=a.y; in[2]=a.z; in[3]=a.w;
  in[4]=b.x; in[5]=b.y; in[6]=b.z; in[7]=b.w;
  in[8]=c.x; in[9]=c.y; in[10]=c.z; in[11]=c.w;
  in[12]=d.x; in[13]=d.y; in[14]=d.z; in[15]=d.w;
}

// ---------- f32 -> packed bf16 conversion (8 elems/thread) ----------
__global__ void k_f2b(const float* __restrict__ src, unsigned short* __restrict__ dst, long n8){
  long t = (long)blockIdx.x*blockDim.x + threadIdx.x;
  if (t >= n8) return;
  const float* p = src + t*8;
  float4 a = *(const float4*)p; float4 b = *(const float4*)(p+4);
  float f[8] = {a.x,a.y,a.z,a.w,b.x,b.y,b.z,b.w};
  *(uint4*)(dst + t*8) = pack8(f);
}

// ---------- CSR build ----------
__global__ void k_count(const int* __restrict__ dst, int* __restrict__ cnt, int n){
  int i = blockIdx.x*blockDim.x + threadIdx.x;
  if (i < n) atomicAdd(&cnt[dst[i]], 1);
}

__global__ void k_blocksum(const int* __restrict__ cnt, int* __restrict__ bsum, int n){
  __shared__ int s[256];
  int i = blockIdx.x*256 + threadIdx.x;
  s[threadIdx.x] = (i < n) ? cnt[i] : 0;
  __syncthreads();
  for (int off=128; off>0; off>>=1){
    if (threadIdx.x < off) s[threadIdx.x] += s[threadIdx.x+off];
    __syncthreads();
  }
  if (threadIdx.x==0) bsum[blockIdx.x] = s[0];
}

__global__ void k_scan_bsum(int* bsum, int nb){
  __shared__ int s[256];
  __shared__ int carry;
  if (threadIdx.x==0) carry = 0;
  __syncthreads();
  for (int base=0; base<nb; base+=256){
    int i = base + threadIdx.x;
    int v = (i<nb) ? bsum[i] : 0;
    s[threadIdx.x] = v; __syncthreads();
    for (int off=1; off<256; off<<=1){
      int t = (threadIdx.x>=off) ? s[threadIdx.x-off] : 0;
      __syncthreads();
      s[threadIdx.x] += t;
      __syncthreads();
    }
    int excl = s[threadIdx.x] - v + carry;
    int tot  = s[255];
    if (i<nb) bsum[i] = excl;
    __syncthreads();
    if (threadIdx.x==0) carry += tot;
    __syncthreads();
  }
}

__global__ void k_scan_add(const int* cnt, const int* __restrict__ bsum,
                           int* __restrict__ rowptr, int* cursor, int n){
  __shared__ int s[256];
  int i = blockIdx.x*256 + threadIdx.x;
  int v = (i<n) ? cnt[i] : 0;
  s[threadIdx.x] = v; __syncthreads();
  for (int off=1; off<256; off<<=1){
    int t = (threadIdx.x>=off) ? s[threadIdx.x-off] : 0;
    __syncthreads();
    s[threadIdx.x] += t;
    __syncthreads();
  }
  int excl = s[threadIdx.x] - v + bsum[blockIdx.x];
  if (i<n){
    rowptr[i] = excl;
    cursor[i] = excl;
    if (i == n-1) rowptr[n] = excl + v;
  }
}

__global__ void k_fill2(const int* __restrict__ src, const int* __restrict__ dst,
                        int* cursor, int* __restrict__ colA, int* __restrict__ colB, int n){
  int i = blockIdx.x*blockDim.x + threadIdx.x;
  if (i < n){
    int p = atomicAdd(&cursor[dst[i]], 1);
    colA[p] = src[i];
    if (colB) colB[p] = i;
  }
}

// ---------- gather spmm (bf16 rows): out[v] = sum over CSR row of src[remap?remap[col]:col]
// 2 threads per row, 8 channels (16B) each
__global__ void __launch_bounds__(256) k_spmm(
    const int* __restrict__ rowptr, const int* __restrict__ col,
    const int* __restrict__ remap,
    const unsigned short* __restrict__ src, unsigned short* __restrict__ out, int nrows){
  int t = blockIdx.x*256 + threadIdx.x;
  int row = t >> 1, half = t & 1;
  if (row >= nrows) return;
  int beg = rowptr[row], end = rowptr[row+1];
  float acc[8] = {0,0,0,0,0,0,0,0};
  const unsigned short* sp = src + (half<<3);
  for (int i=beg; i<end; ++i){
    int c = col[i];
    if (remap) c = remap[c];
    uint4 v = *(const uint4*)(sp + ((size_t)c<<4));
    float f[8]; unpack8(v, f);
    #pragma unroll
    for (int j=0;j<8;j++) acc[j] += f[j];
  }
  *(uint4*)(out + ((size_t)row<<4) + (half<<3)) = pack8(acc);
}

// ---------- fused 6-way projection + bias + relu-merge ----------
// Weights read directly from global with wave-uniform indices -> scalar loads.
__device__ __forceinline__ void accum16(float* acc, const float* in, const float* __restrict__ w){
  #pragma unroll
  for (int o=0;o<32;o++){
    float a = acc[o];
    #pragma unroll
    for (int i=0;i<16;i++) a = fmaf(in[i], w[o*16+i], a);
    acc[o] = a;
  }
}

__global__ void __launch_bounds__(256) k_final(
    const float* __restrict__ base, const float* __restrict__ deg,
    const unsigned short* __restrict__ agg2, const unsigned short* __restrict__ z1,
    const unsigned short* __restrict__ z2, const unsigned short* __restrict__ z4,
    const float* __restrict__ W, const float* __restrict__ Bb,
    float* __restrict__ hout, int nrows){
  int r = blockIdx.x*256 + threadIdx.x;
  if (r >= nrows) return;
  float acc[32];
  #pragma unroll
  for (int o=0;o<32;o++){
    float b = 0.f;
    #pragma unroll
    for (int k=0;k<6;k++) b += Bb[k*32 + o];   // uniform -> scalar loads
    acc[o] = b;
  }
  float in[16];
  loadrow16_f32(base + (size_t)r*16, in);
  accum16(acc, in, W);               // [0] : z
  float dg = deg[r];
  #pragma unroll
  for (int i=0;i<16;i++) in[i] *= dg;
  accum16(acc, in, W + 512);         // [1] : deg * z
  loadrow16_bf(agg2 + (size_t)r*16, in); accum16(acc, in, W + 1024);  // [2]
  loadrow16_bf(z1   + (size_t)r*16, in); accum16(acc, in, W + 1536);  // [3]
  loadrow16_bf(z2   + (size_t)r*16, in); accum16(acc, in, W + 2048);  // [4]
  loadrow16_bf(z4   + (size_t)r*16, in); accum16(acc, in, W + 2560);  // [5]
  float* op = hout + (size_t)r*16;
  float4 o0 = make_float4(acc[0]+fmaxf(acc[16],0.f), acc[1]+fmaxf(acc[17],0.f),
                          acc[2]+fmaxf(acc[18],0.f), acc[3]+fmaxf(acc[19],0.f));
  float4 o1 = make_float4(acc[4]+fmaxf(acc[20],0.f), acc[5]+fmaxf(acc[21],0.f),
                          acc[6]+fmaxf(acc[22],0.f), acc[7]+fmaxf(acc[23],0.f));
  float4 o2 = make_float4(acc[8]+fmaxf(acc[24],0.f), acc[9]+fmaxf(acc[25],0.f),
                          acc[10]+fmaxf(acc[26],0.f), acc[11]+fmaxf(acc[27],0.f));
  float4 o3 = make_float4(acc[12]+fmaxf(acc[28],0.f), acc[13]+fmaxf(acc[29],0.f),
                          acc[14]+fmaxf(acc[30],0.f), acc[15]+fmaxf(acc[31],0.f));
  *(float4*)(op)      = o0;
  *(float4*)(op + 4)  = o1;
  *(float4*)(op + 8)  = o2;
  *(float4*)(op + 12) = o3;
}

// ---------- BN stats reduction over a row region ----------
__global__ void __launch_bounds__(256) k_red(
    const float* __restrict__ h, int nrows, float* __restrict__ stats){
  __shared__ float redS[4][16];
  __shared__ float redQ[4][16];
  float ssum[16], ssq[16];
  #pragma unroll
  for (int c=0;c<16;c++){ ssum[c]=0.f; ssq[c]=0.f; }
  for (long r = (long)blockIdx.x*256 + threadIdx.x; r < nrows; r += (long)gridDim.x*256){
    float in[16];
    loadrow16_f32(h + r*16, in);
    #pragma unroll
    for (int c=0;c<16;c++){ ssum[c] += in[c]; ssq[c] += in[c]*in[c]; }
  }
  int lane = threadIdx.x & 63, wid = threadIdx.x >> 6;
  #pragma unroll
  for (int c=0;c<16;c++){
    float s = ssum[c], q = ssq[c];
    for (int off=32; off; off>>=1){ s += __shfl_xor(s, off, 64); q += __shfl_xor(q, off, 64); }
    if (lane==0){ redS[wid][c] = s; redQ[wid][c] = q; }
  }
  __syncthreads();
  if (threadIdx.x < 16){
    float s=0.f, q=0.f;
    #pragma unroll
    for (int w4=0; w4<4; w4++){ s += redS[w4][threadIdx.x]; q += redQ[w4][threadIdx.x]; }
    atomicAdd(&stats[threadIdx.x], s);
    atomicAdd(&stats[16 + threadIdx.x], q);
  }
}

__global__ void k_stats(const float* __restrict__ st,
                        const float* __restrict__ wx, const float* __restrict__ bx,
                        const float* __restrict__ wy, const float* __restrict__ by,
                        float* __restrict__ prm, int nx, int ny){
  int c = threadIdx.x;
  if (c < 16){
    float m  = st[c]/(float)nx;
    float v  = st[16+c]/(float)nx - m*m;
    float sc = wx[c] * rsqrtf(v + 1e-5f);
    prm[c] = sc; prm[16+c] = bx[c] - m*sc;
    float m2  = st[32+c]/(float)ny;
    float v2  = st[48+c]/(float)ny - m2*m2;
    float sc2 = wy[c] * rsqrtf(v2 + 1e-5f);
    prm[32+c] = sc2; prm[48+c] = by[c] - m2*sc2;
  }
}

__global__ void k_norm(float* __restrict__ out, const float* __restrict__ prm,
                       long nx, long ntot){
  long g = ((long)blockIdx.x*256 + threadIdx.x) * 8;
  if (g >= ntot) return;
  const float* p = (g < nx) ? prm : prm + 32;
  int cbase = (int)(g & 15);
  float4 a = *(float4*)(out + g);
  float4 b = *(float4*)(out + g + 4);
  float f[8] = {a.x,a.y,a.z,a.w,b.x,b.y,b.z,b.w};
  #pragma unroll
  for (int j=0;j<8;j++){ int c = cbase + j; f[j] = f[j]*p[c] + p[16+c]; }
  *(float4*)(out + g)     = make_float4(f[0],f[1],f[2],f[3]);
  *(float4*)(out + g + 4) = make_float4(f[4],f[5],f[6],f[7]);
}

// ---------- host ----------
extern "C" void kernel_launch(void* const* d_in, const int* in_sizes, int n_in,
                              void* d_out, int out_size, void* d_ws, size_t ws_size,
                              hipStream_t stream){
  const float* x      = (const float*)d_in[0];
  const float* y      = (const float*)d_in[1];
  const float* deg_g  = (const float*)d_in[2];
  const float* deg_lg = (const float*)d_in[3];
  const float* thW    = (const float*)d_in[4];
  const float* thB    = (const float*)d_in[5];
  const float* gaW    = (const float*)d_in[6];
  const float* gaB    = (const float*)d_in[7];
  const float* bnxw   = (const float*)d_in[8];
  const float* bnxb   = (const float*)d_in[9];
  const float* bnyw   = (const float*)d_in[10];
  const float* bnyb   = (const float*)d_in[11];
  const int* src_g   = (const int*)d_in[12];
  const int* dst_g   = (const int*)d_in[13];
  const int* src_lg  = (const int*)d_in[14];
  const int* dst_lg  = (const int*)d_in[15];
  const int* eid2nid = (const int*)d_in[16];

  const int N  = in_sizes[2];   // deg_g is (N,1)
  const int E  = in_sizes[3];   // deg_lg is (E,1)
  const int EL = in_sizes[14];  // src_lg

  // workspace carve-out (256B aligned). Peak ~280 MB (yb aliases eb4).
  char* w = (char*)d_ws;
  auto alloc = [&](size_t bytes)->void*{
    void* p = (void*)w; w += (bytes + 255) & ~(size_t)255; return p;
  };
  int* g_cnt      = (int*)alloc((size_t)N*4);
  int* g_rowptr   = (int*)alloc((size_t)(N+1)*4);
  int* g_col_src  = (int*)alloc((size_t)E*4);
  int* g_col_eid  = (int*)alloc((size_t)E*4);
  int* lg_cnt     = (int*)alloc((size_t)E*4);
  int* lg_rowptr  = (int*)alloc((size_t)(E+1)*4);
  int* lg_col     = (int*)alloc((size_t)EL*4);
  int* bsum       = (int*)alloc(8192*4);
  float* stats    = (float*)alloc(64*4);
  float* prm      = (float*)alloc(64*4);
  unsigned short* xb  = (unsigned short*)alloc((size_t)N*16*2);   // bf16 copy of x
  unsigned short* nz1 = (unsigned short*)alloc((size_t)N*16*2);
  unsigned short* nz2 = (unsigned short*)alloc((size_t)N*16*2);
  unsigned short* nz3 = (unsigned short*)alloc((size_t)N*16*2);
  unsigned short* nz4 = (unsigned short*)alloc((size_t)N*16*2);
  unsigned short* nyx = (unsigned short*)alloc((size_t)N*16*2);
  unsigned short* eb1 = (unsigned short*)alloc((size_t)E*16*2);
  unsigned short* eb2 = (unsigned short*)alloc((size_t)E*16*2);
  unsigned short* eb3 = (unsigned short*)alloc((size_t)E*16*2);  // B^3 y, then xy_agg
  unsigned short* yb  = (unsigned short*)alloc((size_t)E*16*2);  // bf16 copy of y; later reused as eb4
  unsigned short* eb4 = yb;  // alias: yb dead before eb4 is written

  hipMemsetAsync(g_cnt, 0, (size_t)N*4, stream);
  hipMemsetAsync(lg_cnt, 0, (size_t)E*4, stream);
  hipMemsetAsync(stats, 0, 64*4, stream);

  // ---- bf16 copies of x and y ----
  long nx8 = (long)N*16/8, ny8 = (long)E*16/8;
  k_f2b<<<(int)((nx8+255)/256), 256, 0, stream>>>(x, xb, nx8);
  k_f2b<<<(int)((ny8+255)/256), 256, 0, stream>>>(y, yb, ny8);

  // ---- CSR for graph g (by dst_g, N rows) ----
  k_count<<<(E+255)/256, 256, 0, stream>>>(dst_g, g_cnt, E);
  int nbg = (N+255)/256;
  k_blocksum<<<nbg, 256, 0, stream>>>(g_cnt, bsum, N);
  k_scan_bsum<<<1, 256, 0, stream>>>(bsum, nbg);
  k_scan_add<<<nbg, 256, 0, stream>>>(g_cnt, bsum, g_rowptr, g_cnt, N);
  k_fill2<<<(E+255)/256, 256, 0, stream>>>(src_g, dst_g, g_cnt, g_col_src, g_col_eid, E);

  // ---- CSR for line graph (by dst_lg, E rows) ----
  k_count<<<(EL+255)/256, 256, 0, stream>>>(dst_lg, lg_cnt, EL);
  int nbl = (E+255)/256;
  k_blocksum<<<nbl, 256, 0, stream>>>(lg_cnt, bsum, E);
  k_scan_bsum<<<1, 256, 0, stream>>>(bsum, nbl);
  k_scan_add<<<nbl, 256, 0, stream>>>(lg_cnt, bsum, lg_rowptr, lg_cnt, E);
  k_fill2<<<(EL+255)/256, 256, 0, stream>>>(src_lg, dst_lg, lg_cnt, lg_col, (int*)nullptr, EL);

  // ---- spmms that read yb first (so eb4 can reuse yb's buffer) ----
  int gs = (2*N+255)/256;
  int es = (2*E+255)/256;
  k_spmm<<<es, 256, 0, stream>>>(lg_rowptr, lg_col, nullptr, yb,  eb1, E);   // B y
  k_spmm<<<gs, 256, 0, stream>>>(g_rowptr, g_col_eid, nullptr, yb, nyx, N);  // sum_e y by dst
  // ---- node branch chain ----
  k_spmm<<<gs, 256, 0, stream>>>(g_rowptr, g_col_src, nullptr, xb,  nz1, N); // A x
  k_spmm<<<gs, 256, 0, stream>>>(g_rowptr, g_col_src, nullptr, nz1, nz2, N); // A^2 x
  k_spmm<<<gs, 256, 0, stream>>>(g_rowptr, g_col_src, nullptr, nz2, nz3, N); // A^3 x
  k_spmm<<<gs, 256, 0, stream>>>(g_rowptr, g_col_src, nullptr, nz3, nz4, N); // A^4 x
  // ---- edge branch chain (yb dead after eb1/nyx; eb4 overwrites it) ----
  k_spmm<<<es, 256, 0, stream>>>(lg_rowptr, lg_col, nullptr, eb1, eb2, E);   // B^2 y
  k_spmm<<<es, 256, 0, stream>>>(lg_rowptr, lg_col, nullptr, eb2, eb3, E);   // B^3 y
  k_spmm<<<es, 256, 0, stream>>>(lg_rowptr, lg_col, nullptr, eb3, eb4, E);   // B^4 y
  k_spmm<<<es, 256, 0, stream>>>(lg_rowptr, lg_col, eid2nid, xb,  eb3, E);   // B (x[eid2nid])

  // ---- fused projections + h ----
  float* outp = (float*)d_out;
  k_final<<<(N+255)/256, 256, 0, stream>>>(x, deg_g, nyx, nz1, nz2, nz4,
                                           thW, thB, outp, N);
  k_final<<<(E+255)/256, 256, 0, stream>>>(y, deg_lg, eb3, eb1, eb2, eb4,
                                           gaW, gaB, outp + (size_t)N*16, E);

  // ---- BN stats + normalize ----
  k_red<<<512, 256, 0, stream>>>(outp, N, stats);
  k_red<<<512, 256, 0, stream>>>(outp + (size_t)N*16, E, stats + 32);
  k_stats<<<1, 64, 0, stream>>>(stats, bnxw, bnxb, bnyw, bnyb, prm, N, E);
  long ntot = (long)(N + E) * 16;
  k_norm<<<(int)((ntot/8 + 255)/256), 256, 0, stream>>>(outp, prm, (long)N*16, ntot);
}